// Round 9
// baseline (1890.261 us; speedup 1.0000x reference)
//
#include <hip/hip_runtime.h>
#include <hip/hip_fp16.h>

typedef _Float16 half2_t __attribute__((ext_vector_type(2)));
typedef unsigned int u32;

// ---------------- problem dims ----------------
constexpr int Bn = 64, Sn = 256, Ln = 9;
constexpr int G4H = 1024;   // 4*H

// ---------------- workspace layout (bytes) ----------------
constexpr size_t XZ_OFF   = 0;                                  // [2][64][256][1024] f32
constexpr size_t XZ_BYTES = (size_t)2 * Bn * Sn * G4H * 4;      // 128 MB
constexpr size_t H_OFF    = XZ_OFF + XZ_BYTES;                  // [64][256][512] f32 (fwd|bwd)
constexpr size_t H_BYTES  = (size_t)Bn * Sn * 512 * 4;          // 32 MB
constexpr size_t UPK_OFF  = H_OFF + H_BYTES;                    // [2][128][1024] u32 (f16 pairs)
constexpr size_t UPK_BYTES= (size_t)2 * 128 * G4H * 4;          // 1 MB
constexpr size_t HX_OFF   = UPK_OFF + UPK_BYTES;                // [128 seq][2 parity][2 half][64] u32
constexpr size_t HX_BYTES = (size_t)128 * 2 * 2 * 64 * 4;       // 128 KB
constexpr size_t FLAG_OFF = HX_OFF + HX_BYTES;                  // [128 seq][2 half][2 parity] u32
constexpr size_t FLAG_BYTES = 128 * 4 * 4;                      // 2 KB

// ---------------- helpers ----------------
__device__ __forceinline__ float sigf(float x) {
  return __fdividef(1.0f, 1.0f + __expf(-x));
}
__device__ __forceinline__ float tanhf_fast(float x) {
  x = fminf(fmaxf(x, -15.0f), 15.0f);
  float e = __expf(-2.0f * x);
  return __fdividef(1.0f - e, 1.0f + e);
}

#if __has_builtin(__builtin_amdgcn_fdot2)
__device__ __forceinline__ float FDOT2(half2_t a, half2_t b, float c) {
  return __builtin_amdgcn_fdot2(a, b, c, false);
}
#else
__device__ __forceinline__ float FDOT2(half2_t a, half2_t b, float c) {
  return c + (float)a.x * (float)b.x + (float)a.y * (float)b.y;
}
#endif

__device__ __forceinline__ half2_t H2(u32 w) { return __builtin_bit_cast(half2_t, w); }
__device__ __forceinline__ half2_t H2F(float f) { return __builtin_bit_cast(half2_t, f); }

// ---------------- kernel 1: pack U (f32 -> f16 pair u32) ----------------
// upk[dir][kp][col]: pair (U[2kp][col], U[2kp+1][col])
__global__ void pack_u(const float* __restrict__ Uf, const float* __restrict__ Ub,
                       u32* __restrict__ upk) {
  int idx = blockIdx.x * 256 + threadIdx.x;      // [2][128][1024]
  if (idx >= 2 * 128 * 1024) return;
  int d  = idx >> 17;
  int kp = (idx >> 10) & 127;
  int j  = idx & 1023;
  const float* U = d ? Ub : Uf;
  _Float16 a = (_Float16)U[(size_t)(2 * kp) * 1024 + j];
  _Float16 b = (_Float16)U[(size_t)(2 * kp + 1) * 1024 + j];
  u32 pa = (u32)__builtin_bit_cast(unsigned short, a);
  u32 pb = (u32)__builtin_bit_cast(unsigned short, b);
  upk[idx] = pa | (pb << 16);
}

// ---------------- kernel 2: xz = gather(emb) @ [Wf|Wb] + bias ----------------
__global__ __launch_bounds__(256, 4)
void xz_gemm(const int* __restrict__ tok, const float* __restrict__ emb,
             const float* __restrict__ Wf, const float* __restrict__ biasf,
             const float* __restrict__ Wb, const float* __restrict__ biasb,
             float* __restrict__ xz) {
  __shared__ float As[32][64];
  __shared__ float Bs[32][128];
  __shared__ int toks[64];
  const int tid = threadIdx.x;
  const int mt = blockIdx.x, nt = blockIdx.y;
  const int d = nt >> 3;
  const float* W    = d ? Wb : Wf;
  const float* bias = d ? biasb : biasf;
  const int n0 = (nt & 7) * 128;
  const int r0 = mt * 64;
  if (tid < 64) toks[tid] = tok[r0 + tid];
  __syncthreads();
  const int tr = tid >> 4, tc = tid & 15;
  float acc[4][8];
#pragma unroll
  for (int j = 0; j < 8; ++j) {
    float bv = bias[n0 + tc * 8 + j];
#pragma unroll
    for (int i = 0; i < 4; ++i) acc[i][j] = bv;
  }
  const int ai = tid >> 2, kq = tid & 3;
  const int kb = tid >> 3, fb = tid & 7;
  for (int k0 = 0; k0 < 256; k0 += 32) {
    const float* ar = emb + (size_t)toks[ai] * 256 + k0 + kq * 8;
    float4 a0 = *(const float4*)ar;
    float4 a1 = *(const float4*)(ar + 4);
    As[kq * 8 + 0][ai] = a0.x; As[kq * 8 + 1][ai] = a0.y;
    As[kq * 8 + 2][ai] = a0.z; As[kq * 8 + 3][ai] = a0.w;
    As[kq * 8 + 4][ai] = a1.x; As[kq * 8 + 5][ai] = a1.y;
    As[kq * 8 + 6][ai] = a1.z; As[kq * 8 + 7][ai] = a1.w;
    const float* wr = W + (size_t)(k0 + kb) * 1024 + n0;
#pragma unroll
    for (int q = 0; q < 4; ++q)
      *(float4*)&Bs[kb][(fb + 8 * q) * 4] = *(const float4*)(wr + (fb + 8 * q) * 4);
    __syncthreads();
#pragma unroll
    for (int kk = 0; kk < 32; ++kk) {
      float4 a4 = *(const float4*)&As[kk][tr * 4];
      float4 b0 = *(const float4*)&Bs[kk][tc * 8];
      float4 b1 = *(const float4*)&Bs[kk][tc * 8 + 4];
      float av[4] = {a4.x, a4.y, a4.z, a4.w};
      float bv[8] = {b0.x, b0.y, b0.z, b0.w, b1.x, b1.y, b1.z, b1.w};
#pragma unroll
      for (int i = 0; i < 4; ++i)
#pragma unroll
        for (int j = 0; j < 8; ++j) acc[i][j] += av[i] * bv[j];
    }
    __syncthreads();
  }
#pragma unroll
  for (int i = 0; i < 4; ++i) {
    int r = r0 + tr * 4 + i;
    int bb_ = r >> 8, s = r & 255;
    float* dst = xz + ((size_t)(d * 64 + bb_) * 256 + s) * 1024 + n0 + tc * 8;
    float4 o0 = {acc[i][0], acc[i][1], acc[i][2], acc[i][3]};
    float4 o1 = {acc[i][4], acc[i][5], acc[i][6], acc[i][7]};
    *(float4*)dst = o0;
    *(float4*)(dst + 4) = o1;
  }
}

// ---------------- kernel 3: LSTM recurrence, 2 CUs per sequence ----------------
// 256 blocks x 512 threads. Block = (seq, half): owns hidden units
// [128*half, 128*half+128) -> 512 gate cols. U slice = 256 KB f16:
// own-half k-pairs (64) + partner pairs 0..23 in VGPRs (88 regs, fits the
// 128 cap WITHOUT spill), partner pairs 24..63 in LDS (80 KB). Per step:
// z_own from local h while partner h-half (256 B) arrives via L2 mailbox
// (parity slots, monotonic flags, release/acquire agent atomics, all by
// wave 0 so vmcnt(0) at the flag only covers the 64 mailbox stores).
__global__ __launch_bounds__(512)
void lstm_seq(const float* __restrict__ xz, const u32* __restrict__ upk,
              float* __restrict__ h_out, u32* __restrict__ hx, u32* __restrict__ flags) {
  const int bid  = blockIdx.x;         // 0..255
  const int seq  = bid >> 1;           // dir*64 + b
  const int half = bid & 1;
  const int dir  = seq >> 6;
  const int tid  = threadIdx.x;
  const int g    = tid >> 7;           // gate 0..3
  const int m    = tid & 127;          // unit index within half
  const int jcol = g * 256 + 128 * half + m;   // global gate col 0..1023

  __shared__ uint4 ul[10][512];        // partner U pairs 24..63: 80 KB
  __shared__ float zbuf[512];          // 2 KB
  __shared__ __align__(16) u32 h2[128];// full h as packed f16 pairs, 512 B

  const u32* ub = upk + (size_t)dir * 131072 + jcol;
  const int ob = 64 * half;            // own pair base in h2
  const int pb = 64 * (1 - half);      // partner pair base in h2

  // --- U: own 64 pairs + partner first 24 pairs in VGPRs ---
  float uo[64], up[24];
#pragma unroll
  for (int q = 0; q < 64; ++q)
    uo[q] = __builtin_bit_cast(float, ub[(size_t)(ob + q) * 1024]);
#pragma unroll
  for (int q = 0; q < 24; ++q)
    up[q] = __builtin_bit_cast(float, ub[(size_t)(pb + q) * 1024]);
  // --- U: partner pairs 24..63 into LDS ---
#pragma unroll
  for (int r = 0; r < 10; ++r) {
    uint4 v;
    v.x = ub[(size_t)(pb + 24 + 4 * r + 0) * 1024];
    v.y = ub[(size_t)(pb + 24 + 4 * r + 1) * 1024];
    v.z = ub[(size_t)(pb + 24 + 4 * r + 2) * 1024];
    v.w = ub[(size_t)(pb + 24 + 4 * r + 3) * 1024];
    ul[r][tid] = v;
  }
  if (tid < 128) h2[tid] = 0u;

  u32* mbp  = hx + (size_t)seq * 256;            // [parity][half][64]
  u32* mymb = mbp + half * 64;                   // + p*128 + lane
  u32* pamb = mbp + (1 - half) * 64;             // + p*128 + lane
  u32* myfl = flags + seq * 4 + half * 2;        // + p
  u32* pafl = flags + seq * 4 + (1 - half) * 2;  // + p

  float* hop = h_out + (size_t)(seq & 63) * 256 * 512 + dir * 256 + 128 * half;
  const float* xzp = xz + (size_t)seq * 256 * 1024 + jcol;

  float c0 = 0.0f, c1 = 0.0f;
  __syncthreads();

  float xc = xzp[(size_t)(dir ? 255 : 0) * 1024];

  for (int t = 0; t < 256; ++t) {
    const int scur  = dir ? (255 - t) : t;
    const int snext = (t < 255) ? (dir ? (254 - t) : (t + 1)) : (dir ? 255 : 0);

    // ---- exchange-in: wave 0 pulls partner h-half (t>=1) ----
    if (tid < 64 && t >= 1) {
      const int pp = (t - 1) & 1;
      if (tid == 0) {
        while (__hip_atomic_load(pafl + pp, __ATOMIC_ACQUIRE, __HIP_MEMORY_SCOPE_AGENT)
               < (u32)t)
          __builtin_amdgcn_s_sleep(1);
      }
      u32 v = __hip_atomic_load(pamb + pp * 128 + tid, __ATOMIC_RELAXED,
                                __HIP_MEMORY_SCOPE_AGENT);
      h2[pb + tid] = v;
    }

    // ---- z_own: own-half k pairs (regs), local h (stable) ----
    float acc = xc;
#pragma unroll
    for (int cc = 0; cc < 16; ++cc) {
      uint4 hh = *(const uint4*)&h2[ob + 4 * cc];
      acc = FDOT2(H2(hh.x), H2F(uo[4 * cc + 0]), acc);
      acc = FDOT2(H2(hh.y), H2F(uo[4 * cc + 1]), acc);
      acc = FDOT2(H2(hh.z), H2F(uo[4 * cc + 2]), acc);
      acc = FDOT2(H2(hh.w), H2F(uo[4 * cc + 3]), acc);
    }
    __syncthreads();   // partner half now in h2

    // ---- z_partner: pairs pb..pb+23 (regs) + pb+24..pb+63 (LDS) ----
#pragma unroll
    for (int cc = 0; cc < 6; ++cc) {
      uint4 hh = *(const uint4*)&h2[pb + 4 * cc];
      acc = FDOT2(H2(hh.x), H2F(up[4 * cc + 0]), acc);
      acc = FDOT2(H2(hh.y), H2F(up[4 * cc + 1]), acc);
      acc = FDOT2(H2(hh.z), H2F(up[4 * cc + 2]), acc);
      acc = FDOT2(H2(hh.w), H2F(up[4 * cc + 3]), acc);
    }
#pragma unroll
    for (int r = 0; r < 10; ++r) {
      uint4 hh = *(const uint4*)&h2[pb + 24 + 4 * r];
      uint4 va = ul[r][tid];
      acc = FDOT2(H2(hh.x), H2(va.x), acc);
      acc = FDOT2(H2(hh.y), H2(va.y), acc);
      acc = FDOT2(H2(hh.z), H2(va.z), acc);
      acc = FDOT2(H2(hh.w), H2(va.w), acc);
    }
    zbuf[tid] = acc;
    __syncthreads();

    // ---- gates + publish: wave 0 only (2 units/lane) ----
    float h0 = 0.0f, h1 = 0.0f;
    if (tid < 64) {
      const int u0 = 2 * tid;
      float zi0 = zbuf[u0],     zf0 = zbuf[128 + u0];
      float zg0 = zbuf[256 + u0], zo0 = zbuf[384 + u0];
      float zi1 = zbuf[u0 + 1], zf1 = zbuf[129 + u0];
      float zg1 = zbuf[257 + u0], zo1 = zbuf[385 + u0];
      c0 = sigf(zf0) * c0 + sigf(zi0) * tanhf_fast(zg0);
      h0 = sigf(zo0) * tanhf_fast(c0);
      c1 = sigf(zf1) * c1 + sigf(zi1) * tanhf_fast(zg1);
      h1 = sigf(zo1) * tanhf_fast(c1);
      u32 p0 = (u32)__builtin_bit_cast(unsigned short, (_Float16)h0);
      u32 p1 = (u32)__builtin_bit_cast(unsigned short, (_Float16)h1);
      u32 pk = p0 | (p1 << 16);
      h2[ob + tid] = pk;                       // local own half
      if (t < 255) {
        __hip_atomic_store(mymb + (t & 1) * 128 + tid, pk, __ATOMIC_RELAXED,
                           __HIP_MEMORY_SCOPE_AGENT);
        if (tid == 0)
          __hip_atomic_store(myfl + (t & 1), (u32)(t + 1), __ATOMIC_RELEASE,
                             __HIP_MEMORY_SCOPE_AGENT);
      }
    }
    asm volatile("" ::: "memory");   // keep the prefetch below AFTER the flag
    float nx = xzp[(size_t)snext * 1024];
    if (tid < 64) {
      float2 hv = {h0, h1};
      *(float2*)&hop[(size_t)scur * 512 + 2 * tid] = hv;
    }
    __syncthreads();
    xc = nx;
  }
}

// ---------------- kernel 4: logits = h @ W_dense + b_dense ----------------
__global__ __launch_bounds__(256, 4)
void logits_k(const float* __restrict__ h_out, const float* __restrict__ Wd,
              const float* __restrict__ bd, float* __restrict__ out) {
  __shared__ float Ws[512 * 9];
  __shared__ float bs[16];
  const int tid = threadIdx.x;
  for (int i = tid; i < 4608; i += 256) Ws[i] = Wd[i];
  if (tid < 9) bs[tid] = bd[tid];
  __syncthreads();
  const int w = tid >> 6, lane = tid & 63;
  const int r0 = blockIdx.x * 16 + w * 4;
  for (int rr = 0; rr < 4; ++rr) {
    const int r = r0 + rr;
    const float* hp = h_out + (size_t)r * 512 + lane * 8;
    float4 h0 = *(const float4*)hp;
    float4 h1 = *(const float4*)(hp + 4);
    float hv[8] = {h0.x, h0.y, h0.z, h0.w, h1.x, h1.y, h1.z, h1.w};
    float outv = 0.0f;
#pragma unroll
    for (int l = 0; l < 9; ++l) {
      float p = 0.0f;
#pragma unroll
      for (int uu = 0; uu < 8; ++uu) p += hv[uu] * Ws[(lane * 8 + uu) * 9 + l];
      for (int off = 32; off; off >>= 1) p += __shfl_xor(p, off, 64);
      if (lane == l) outv = p;
    }
    if (lane < 9) out[(size_t)r * 9 + lane] = outv + bs[lane];
  }
}

// ---------------- kernel 5: CRF log-likelihood ----------------
__global__ void crf_k(const float* __restrict__ logits, const int* __restrict__ label,
                      const int* __restrict__ mask, const float* __restrict__ trans,
                      float* __restrict__ out_ll, float* __restrict__ out_trans) {
  const int b = blockIdx.x;
  const int lane = threadIdx.x;
  int cnt = 0;
#pragma unroll
  for (int q = 0; q < 4; ++q) cnt += (mask[b * 256 + lane + q * 64] != 0) ? 1 : 0;
  for (int off = 32; off; off >>= 1) cnt += __shfl_xor(cnt, off, 64);
  const int len = cnt;
  float un = 0.0f;
#pragma unroll
  for (int q = 0; q < 4; ++q) {
    int s = lane + q * 64;
    if (s < len) un += logits[((size_t)b * 256 + s) * 9 + label[b * 256 + s]];
  }
  for (int off = 32; off; off >>= 1) un += __shfl_xor(un, off, 64);
  float bin = 0.0f;
#pragma unroll
  for (int q = 0; q < 4; ++q) {
    int s = lane + q * 64;
    if (s < 255 && s < len - 1)
      bin += trans[label[b * 256 + s] * 9 + label[b * 256 + s + 1]];
  }
  for (int off = 32; off; off >>= 1) bin += __shfl_xor(bin, off, 64);
  float alpha = (lane < 9) ? logits[((size_t)b * 256) * 9 + lane] : -INFINITY;
  float tcol[9];
  if (lane < 9) {
#pragma unroll
    for (int i = 0; i < 9; ++i) tcol[i] = trans[i * 9 + lane];
  }
  for (int t = 1; t < 256; ++t) {
    float a[9];
#pragma unroll
    for (int i = 0; i < 9; ++i) a[i] = __shfl(alpha, i, 64);
    if (lane < 9) {
      float mx = a[0] + tcol[0];
#pragma unroll
      for (int i = 1; i < 9; ++i) mx = fmaxf(mx, a[i] + tcol[i]);
      float ssum = 0.0f;
#pragma unroll
      for (int i = 0; i < 9; ++i) ssum += __expf(a[i] + tcol[i] - mx);
      float nw = mx + __logf(ssum) + logits[((size_t)b * 256 + t) * 9 + lane];
      if (t < len) alpha = nw;
    }
  }
  float mx = alpha;
  for (int off = 32; off; off >>= 1) mx = fmaxf(mx, __shfl_xor(mx, off, 64));
  float e = __expf(alpha - mx);
  for (int off = 32; off; off >>= 1) e += __shfl_xor(e, off, 64);
  if (lane == 0) out_ll[b] = un + bin - (mx + __logf(e));
  if (b == 0) {
    for (int i = lane; i < 81; i += 64) out_trans[i] = trans[i];
  }
}

// ---------------- launch ----------------
extern "C" void kernel_launch(void* const* d_in, const int* in_sizes, int n_in,
                              void* d_out, int out_size, void* d_ws, size_t ws_size,
                              hipStream_t stream) {
  (void)in_sizes; (void)n_in; (void)out_size; (void)ws_size;
  const int*   inputs = (const int*)d_in[0];
  const int*   amask  = (const int*)d_in[1];
  const int*   label  = (const int*)d_in[2];
  const float* emb    = (const float*)d_in[3];
  const float* Wf     = (const float*)d_in[4];
  const float* Uf     = (const float*)d_in[5];
  const float* bf     = (const float*)d_in[6];
  const float* Wb     = (const float*)d_in[7];
  const float* Ub     = (const float*)d_in[8];
  const float* bb     = (const float*)d_in[9];
  const float* Wd     = (const float*)d_in[10];
  const float* bd     = (const float*)d_in[11];
  const float* trans  = (const float*)d_in[12];

  char* ws = (char*)d_ws;
  float* xz    = (float*)(ws + XZ_OFF);
  float* h_out = (float*)(ws + H_OFF);
  u32*   upk   = (u32*)(ws + UPK_OFF);
  u32*   hx    = (u32*)(ws + HX_OFF);
  u32*   flags = (u32*)(ws + FLAG_OFF);

  float* out      = (float*)d_out;
  float* out_ll   = out + (size_t)Bn * Sn * Ln;        // 147456
  float* out_tr   = out_ll + Bn;                       // 147520

  hipMemsetAsync(flags, 0, FLAG_BYTES, stream);
  pack_u<<<1024, 256, 0, stream>>>(Uf, Ub, upk);
  xz_gemm<<<dim3(256, 16), 256, 0, stream>>>(inputs, emb, Wf, bf, Wb, bb, xz);
  lstm_seq<<<256, 512, 0, stream>>>(xz, upk, h_out, hx, flags);
  logits_k<<<1024, 256, 0, stream>>>(h_out, Wd, bd, out);
  crf_k<<<64, 64, 0, stream>>>(out, label, amask, trans, out_ll, out_tr);
}